// Round 17
// baseline (193.660 us; speedup 1.0000x reference)
//
#include <hip/hip_runtime.h>

// Problem constants (from reference)
#define HH 4096
#define WW 4096
#define NB 1024
#define NCHUNK 256
#define CROWS 16          // HH / NCHUNK
#define IOU_T 0.5f
#define NBLK_STAGE 1024   // (NCHUNK * WW/4) / 256
#define NBLK_TAIL 256     // 1 block/CU (144 KB LDS), 1024 thr = 16 waves/CU

typedef unsigned long long u64;

// ---------------- workspace layout ------------------------------------------
// Counter region: 8 KB, ONE counter per 128 B line (R10 lesson).
//  line 0           : master M            (ctrs[0])
//  lines 1..32      : barrier arrival A[g](ctrs[32*(1+g)]), g = blockIdx>>3
constexpr size_t OFF_PART   = 0;                                   // double x NCHUNK*WW (8 MB)
constexpr size_t OFF_SC64   = OFF_PART   + (size_t)NCHUNK * WW * 8;// double x NB
constexpr size_t OFF_ORDER  = OFF_SC64   + (size_t)NB * 8;         // int x NB
constexpr size_t OFF_CTR    = OFF_ORDER  + (size_t)NB * 4;         // int x 2048 (8 KB)
constexpr size_t OFF_IOU    = OFF_CTR    + 8192;                   // u64 x NB*16 (128 KB)
constexpr size_t OFF_RECSC  = OFF_IOU    + (size_t)NB * 16 * 8;    // double x NB
constexpr size_t OFF_RECSEL = OFF_RECSC  + (size_t)NB * 8;         // u64 x NB*16 (128 KB)
constexpr size_t OFF_CC     = OFF_RECSEL + (size_t)NB * 16 * 8;    // float x HH*WW (64 MB)
constexpr size_t OFF_PART2  = OFF_CC     + (size_t)HH * WW * 4;    // double x NCHUNK*WW (8 MB)

// ---------------- sc1 (coherent-point) helpers ------------------------------
// Agent-scope RELAXED atomics compile to global_load/store sc1: bypass the
// per-XCD L2, hit the shared coherent point, emit NO cache-walk ops (R1/R2
// lesson). Discipline (validated R4-R16, absmax 0.0 every round): producers
// st_c into buffers no XCD cached earlier in the kernel; consumers use
// NORMAL loads. sc1 stores must be LANE-CONTIGUOUS per instruction or the
// LLC does partial-line RMW at ~4x bytes (R7 +25us bug).
template <typename T>
__device__ __forceinline__ void st_c(T* p, T v) {
    __hip_atomic_store(p, v, __ATOMIC_RELAXED, __HIP_MEMORY_SCOPE_AGENT);
}

// R12 sharded flat barrier (256 co-resident blocks), agent-scope ONLY:
// arrival on 32 line-padded counters (8 blocks each, parallel across LLC
// banks); group closers RMW the master; everyone polls the master.
__device__ __forceinline__ void gbar(int* ctrs, int round) {
    asm volatile("s_waitcnt vmcnt(0)" ::: "memory");
    __syncthreads();
    if (threadIdx.x == 0) {
        int g = blockIdx.x >> 3;      // 0..31, 8 blocks each
        int a = __hip_atomic_fetch_add(&ctrs[32 * (1 + g)], 1,
                                       __ATOMIC_RELAXED, __HIP_MEMORY_SCOPE_AGENT);
        if (a == 8 * round - 1)       // group closer
            __hip_atomic_fetch_add(&ctrs[0], 1, __ATOMIC_RELAXED,
                                   __HIP_MEMORY_SCOPE_AGENT);
        while (__hip_atomic_load(&ctrs[0], __ATOMIC_RELAXED,
                                 __HIP_MEMORY_SCOPE_AGENT) < 32 * round)
            __builtin_amdgcn_s_sleep(2);
    }
    __syncthreads();
}

// ---------------- kernels ---------------------------------------------------

// staging, PURE (verified R13-session body; <41 us measured via R16's split).
// Normal cached stores of Cc + part, published by the dispatch boundary.
// R17: block 0 additionally zeroes the 64 line-padded barrier counters via
// sc1 (saves the memset dispatch + its ~10 us gap; R6-verified pattern —
// ordered before k_tail by the dispatch boundary).
__global__ void __launch_bounds__(256) k_stage(const float* __restrict__ probs,
        const float* __restrict__ bbox,
        double* __restrict__ part, float* __restrict__ Cc, int* __restrict__ ctrs) {
    __shared__ int xlo_s[CROWS], xhi_s[CROWS];
    __shared__ int2 rng_s[CROWS];   // {q0, q1} col-quad range; {1,0} if unflagged
    int tid = blockIdx.x * 256 + threadIdx.x;   // NCHUNK * WW/4 threads
    int c  = tid >> 10;          // chunk (uniform per block)
    int xq = tid & 1023;         // col-quad index
    int t  = threadIdx.x;
    if (blockIdx.x == 0 && t < 64) st_c(&ctrs[t * 32], 0);   // all counter lines
    if (t < CROWS) { xlo_s[t] = WW + 1; xhi_s[t] = -1; }
    __syncthreads();
    int r0 = c * CROWS;
    for (int i = t; i < NB; i += 256) {
        float4 bb = ((const float4*)bbox)[i];
        int x1 = min(max((int)floorf(bb.x), 0), WW);
        int y1 = min(max((int)floorf(bb.y), 0), HH);
        int x2 = min(max((int)floorf(bb.z), 0), WW);
        int y2 = min(max((int)floorf(bb.w), 0), HH);
        int ra = y1 - 1 - r0, rb = y2 - 1 - r0;
        if (ra >= 0 && ra < CROWS) { atomicMin(&xlo_s[ra], x1); atomicMax(&xhi_s[ra], x2); }
        if (rb >= 0 && rb < CROWS) { atomicMin(&xlo_s[rb], x1); atomicMax(&xhi_s[rb], x2); }
    }
    __syncthreads();
    if (t < CROWS) {
        int lo = xlo_s[t], hi = xhi_s[t];
        rng_s[t] = (hi >= 0) ? make_int2(lo >> 2, (hi + 3) >> 2) : make_int2(1, 0);
    }
    __syncthreads();
    const float4* p = (const float4*)probs + (size_t)r0 * (WW / 4) + xq;
    float4* Cc4 = (float4*)Cc;
    double a0 = 0.0, a1 = 0.0, a2 = 0.0, a3 = 0.0;
    for (int r = 0; r < CROWS; r += 8) {
        float4 q[8];
        #pragma unroll
        for (int k = 0; k < 8; k++) q[k] = p[(size_t)(r + k) * (WW / 4)];
        #pragma unroll
        for (int k = 0; k < 8; k++) {
            a0 += (double)q[k].x; a1 += (double)q[k].y;
            a2 += (double)q[k].z; a3 += (double)q[k].w;
            int2 d = rng_s[r + k];
            if (xq >= d.x && xq < d.y)
                Cc4[(size_t)(r0 + r + k) * (WW / 4) + xq] =
                    make_float4((float)a0, (float)a1, (float)a2, (float)a3);
        }
    }
    double2* pp = (double2*)(part + (size_t)c * WW) + xq * 2;
    pp[0] = make_double2(a0, a1);
    pp[1] = make_double2(a2, a3);
}

// fused tail: P0 chunkscan -> boxsum -> rank -> iou -> group -> final.
// 256 blocks x 1024 threads (16 waves/CU), 5 sharded barriers.
// R17: the chunkscan dispatch is folded in as P0 on blocks 0..3 (4096
// columns, one per thread, the proven batched shape). Output goes via
// LANE-CONTIGUOUS sc1 stores into FRESH part2 (in-place normal stores would
// strand dirty lines in the scanners' XCD L2s -> stale cross-XCD reads);
// P1 then reads part2 with normal loads (validated R6 P0b->P1 contract).
__global__ void __launch_bounds__(1024) k_tail(const float* __restrict__ bbox,
        const float* __restrict__ obj,
        const float* __restrict__ Cc,
        const double* __restrict__ part,
        double* __restrict__ part2,
        const int* __restrict__ counts,
        double* __restrict__ sc64, int* __restrict__ order,
        u64* __restrict__ ioub, double* __restrict__ recsc,
        u64* __restrict__ recsel, int* __restrict__ ctrs,
        float* __restrict__ out) {
    __shared__ double s_sc[NB];                 // 8 KB, unsorted scores
    __shared__ int    ord_s[NB];                // 4 KB, sorted->orig index
    __shared__ alignas(16) u64 big[NB * 16];    // 128 KB: sbb (P3) / iou rows (P4)
    __shared__ double red[16];                  // P1 cross-wave reduce
    __shared__ int    redi[16];                 // P2 cross-wave reduce
    float4* sbb = (float4*)big;                 // first 16 KB alias
    int b = blockIdx.x, t = threadIdx.x;

    // ---- P0: exclusive scan of part along the chunk axis; blocks 0..3,
    // one column per thread (coalesced), batched 16-deep. part read normal
    // (published by the k_stage dispatch boundary); part2 written sc1
    // lane-contiguous.
    if (b < 4) {
        int x = b * 1024 + t;       // 4 blocks x 1024 threads = 4096 columns
        double carry = 0.0;
        for (int g = 0; g < NCHUNK / 16; g++) {
            double v[16];
            #pragma unroll
            for (int k = 0; k < 16; k++) v[k] = part[(size_t)(g * 16 + k) * WW + x];
            #pragma unroll
            for (int k = 0; k < 16; k++) { double tv = v[k]; v[k] = carry; carry += tv; }
            #pragma unroll
            for (int k = 0; k < 16; k++)
                st_c(&part2[(size_t)(g * 16 + k) * WW + x], v[k]);
        }
    }
    gbar(ctrs, 1);

    // ---- P1: boxsum, 4 boxes/block x 256 threads each. Column value =
    // within-chunk fp32 cumsum row (Cc) + fp64 chunk prefix (part2, 16-row
    // chunks -> index (y-1)>>4), normal cacheable loads.
    {
        int bg = t >> 8;            // box group 0..3 (waves 4bg..4bg+3)
        int tl = t & 255;
        int i = b * 4 + bg;
        float4 bb = ((const float4*)bbox)[i];
        int x1 = min(max((int)floorf(bb.x), 0), WW);
        int y1 = min(max((int)floorf(bb.y), 0), HH);
        int x2 = min(max((int)floorf(bb.z), 0), WW);
        int y2 = min(max((int)floorf(bb.w), 0), HH);
        bool h1 = (y1 >= 1), h2 = (y2 >= 1);
        const float*  r2 = Cc    + (size_t)(h2 ? (y2 - 1) : 0) * WW;
        const double* q2 = part2 + (size_t)(h2 ? ((y2 - 1) >> 4) : 0) * WW;
        const float*  r1 = Cc    + (size_t)(h1 ? (y1 - 1) : 0) * WW;
        const double* q1 = part2 + (size_t)(h1 ? ((y1 - 1) >> 4) : 0) * WW;
        double s = 0.0;
        for (int x = x1 + tl; x < x2; x += 256) {
            double v2 = h2 ? ((double)r2[x] + q2[x]) : 0.0;
            double v1 = h1 ? ((double)r1[x] + q1[x]) : 0.0;
            s += (v2 - v1);
        }
        #pragma unroll
        for (int off = 32; off > 0; off >>= 1) s += __shfl_down(s, off);
        if ((t & 63) == 0) red[t >> 6] = s;
        __syncthreads();
        if (tl == 0) {
            double tot = red[bg * 4] + red[bg * 4 + 1] + red[bg * 4 + 2] + red[bg * 4 + 3];
            long long cnt = (long long)(y2 - y1) * (long long)(x2 - x1);
            if (cnt < 1) cnt = 1;
            st_c(&sc64[i], 0.5 * ((double)obj[i] + tot / (double)cnt));
        }
    }
    gbar(ctrs, 2);

    // ---- P2: stable descending rank, DISTRIBUTED: 4 boxes/block, 256
    // threads per box, 4 j's per thread; shuffle + LDS reduce -> sc1 order.
    s_sc[t] = sc64[t];              // normal loads (sc1-written, fresh)
    __syncthreads();
    {
        int bg = t >> 8;            // box slot 0..3
        int tl = t & 255;
        int i = b * 4 + bg;
        double si = s_sc[i];
        int p = 0;
        #pragma unroll
        for (int it = 0; it < 4; it++) {
            int j = tl * 4 + it;
            double sj = s_sc[j];
            p += (sj > si) || (sj == si && j < i);
        }
        #pragma unroll
        for (int off = 32; off > 0; off >>= 1) p += __shfl_down(p, off);
        if ((t & 63) == 0) redi[t >> 6] = p;
        __syncthreads();
        if (t < 4) {
            int r = redi[t * 4] + redi[t * 4 + 1] + redi[t * 4 + 2] + redi[t * 4 + 3];
            st_c(&order[r], b * 4 + t);
        }
    }
    gbar(ctrs, 3);

    // ---- P3: IoU(sorted_i, sorted_j) > 0.5 bit matrix; 4 rows/block.
    // Full order gathered (fresh buffer, 4 KB) + sorted bboxes into LDS.
    {
        int o = order[t];           // normal load
        ord_s[t] = o;
        sbb[t] = ((const float4*)bbox)[o];
    }
    __syncthreads();
    {
        int l = t & 63;
        for (int task = t >> 6; task < 64; task += 16) {
            int r = task >> 4, wd = task & 15;
            int i = b * 4 + r;
            float4 a = sbb[i];
            float ai = (a.z - a.x) * (a.w - a.y);
            float4 bb = sbb[(wd << 6) + l];
            float aj = (bb.z - bb.x) * (bb.w - bb.y);
            float ix1 = fmaxf(a.x, bb.x), iy1 = fmaxf(a.y, bb.y);
            float ix2 = fminf(a.z, bb.z), iy2 = fminf(a.w, bb.w);
            float iw = fmaxf(ix2 - ix1, 0.0f), ih = fmaxf(iy2 - iy1, 0.0f);
            float inter = iw * ih;
            float iou_v = inter / (ai + aj - inter);
            u64 m = __ballot(iou_v > IOU_T);
            if (l == 0) st_c(&ioub[(size_t)i * 16 + wd], m);
        }
    }
    gbar(ctrs, 4);

    // ---- P4: greedy grouping, 4 starts/block; FULL ioub staged into LDS
    // (coalesced 128 KB, LLC-amortized) so the serial greedy chain reads
    // ~120cy LDS rows instead of ~900cy cold global rows.
    #pragma unroll
    for (int k = 0; k < 16; k++) big[t + k * 1024] = ioub[t + k * 1024];
    __syncthreads();
    {
        int K = counts[0];
        if (t < 4) {
            int i = b * 4 + t;
            u64 inc[16], sel[16];
            int wi = i >> 6, bi = i & 63;
            #pragma unroll
            for (int w = 0; w < 16; w++) {
                inc[w] = big[i * 16 + w];
                sel[w] = (w == wi) ? (1ULL << bi) : 0ULL;
            }
            int size = 1;
            double score = s_sc[ord_s[i]];
            int last = i;
            #pragma unroll
            for (int w = 0; w < 16; w++) {
                if (w < wi || size >= K) continue;
                u64 avail = ~inc[w];
                if (w == wi) avail &= (bi == 63) ? 0ULL : (~0ULL << (bi + 1));
                while (avail != 0ULL && size < K) {
                    int bj = __builtin_ctzll(avail);
                    int j = (w << 6) + bj;
                    sel[w] |= 1ULL << bj;
                    size++;
                    score += s_sc[ord_s[j]];
                    last = j;
                    const u64* rj = &big[j * 16];
                    #pragma unroll
                    for (int w2 = 0; w2 < 16; w2++) inc[w2] |= rj[w2];
                    avail &= ~inc[w];          // row j's own bits clear bj et al.
                    avail &= ~(1ULL << bj);    // safety
                }
            }
            int rec = (size == K) && (last < NB - 1);
            st_c(&recsc[i], rec ? score : -1e300);
            #pragma unroll
            for (int w = 0; w < 16; w++) st_c(&recsel[(size_t)i * 16 + w], sel[w]);
        }
    }
    gbar(ctrs, 5);
    if (b != 0) return;

    // ---- P5: final last-argmax + output scatter (block 0, wave 0).
    if (t < 64) {
        double bs = -1e301; int bidx = 0;
        for (int m = 0; m < 16; m++) {
            int k = t * 16 + m;        // increasing k; >= keeps the last
            double v = recsc[k];       // normal load (fresh buffer)
            if (v >= bs) { bs = v; bidx = k; }
        }
        #pragma unroll
        for (int off = 32; off > 0; off >>= 1) {
            double ob = __shfl_down(bs, off);
            int oi = __shfl_down(bidx, off);
            if (ob > bs || (ob == bs && oi > bidx)) { bs = ob; bidx = oi; }
        }
        bs = __shfl(bs, 0);
        bidx = __shfl(bidx, 0);
        int any = bs > -1e299;
        for (int k = t; k < NB; k += 64) {
            float v = 0.0f;
            if (any && ((recsel[(size_t)bidx * 16 + (k >> 6)] >> (k & 63)) & 1ULL))
                v = (float)s_sc[ord_s[k]];
            out[k] = v;
        }
    }
}

// ---------------- host entry ------------------------------------------------

extern "C" void kernel_launch(void* const* d_in, const int* in_sizes, int n_in,
                              void* d_out, int out_size, void* d_ws, size_t ws_size,
                              hipStream_t stream) {
    const float* bbox  = (const float*)d_in[0];
    const float* obj   = (const float*)d_in[1];
    const float* probs = (const float*)d_in[2];
    const int*   counts = (const int*)d_in[3];
    float* out = (float*)d_out;

    char* w = (char*)d_ws;
    double* part    = (double*)(w + OFF_PART);
    double* sc64    = (double*)(w + OFF_SC64);
    int*    order   = (int*)(w + OFF_ORDER);
    int*    ctrs    = (int*)(w + OFF_CTR);
    u64*    ioub    = (u64*)(w + OFF_IOU);
    double* recsc   = (double*)(w + OFF_RECSC);
    u64*    recsel  = (u64*)(w + OFF_RECSEL);
    float*  Cc      = (float*)(w + OFF_CC);
    double* part2   = (double*)(w + OFF_PART2);

    k_stage<<<NBLK_STAGE, 256, 0, stream>>>(probs, bbox, part, Cc, ctrs);
    k_tail<<<NBLK_TAIL, 1024, 0, stream>>>(bbox, obj, Cc, part, part2, counts,
                                           sc64, order, ioub, recsc,
                                           recsel, ctrs, out);
}

// Round 18
// 149.616 us; speedup vs baseline: 1.2944x; 1.2944x over previous
//
#include <hip/hip_runtime.h>

// Problem constants (from reference)
#define HH 4096
#define WW 4096
#define NB 1024
#define NCHUNK 256
#define CROWS 16          // HH / NCHUNK
#define IOU_T 0.5f
#define NBLK_STAGE 1024   // (NCHUNK * WW/4) / 256
#define NBLK_TAIL 256     // 1 block/CU (144 KB LDS), 1024 thr = 16 waves/CU

typedef unsigned long long u64;

// ---------------- workspace layout ------------------------------------------
// Counter region: 8 KB, ONE counter per 128 B line (R10 lesson).
//  line 0           : master M            (ctrs[0])
//  lines 1..32      : barrier arrival A[g](ctrs[32*(1+g)]), g = blockIdx>>3
constexpr size_t OFF_PART   = 0;                                   // double x NCHUNK*WW (8 MB)
constexpr size_t OFF_SC64   = OFF_PART   + (size_t)NCHUNK * WW * 8;// double x NB
constexpr size_t OFF_ORDER  = OFF_SC64   + (size_t)NB * 8;         // int x NB
constexpr size_t OFF_CTR    = OFF_ORDER  + (size_t)NB * 4;         // int x 2048 (8 KB)
constexpr size_t OFF_IOU    = OFF_CTR    + 8192;                   // u64 x NB*16 (128 KB)
constexpr size_t OFF_RECSC  = OFF_IOU    + (size_t)NB * 16 * 8;    // double x NB
constexpr size_t OFF_RECSEL = OFF_RECSC  + (size_t)NB * 8;         // u64 x NB*16 (128 KB)
constexpr size_t OFF_CC     = OFF_RECSEL + (size_t)NB * 16 * 8;    // float x HH*WW (64 MB)

// ---------------- sc1 (coherent-point) helpers ------------------------------
// Agent-scope RELAXED atomics compile to global_load/store sc1: bypass the
// per-XCD L2, hit the shared coherent point, emit NO cache-walk ops (R1/R2
// lesson). Discipline (validated R4-R17, absmax 0.0 every round): producers
// st_c into buffers no XCD cached earlier in the kernel; consumers use
// NORMAL loads. R17 lesson: sc1 BULK streams need many blocks — 4 blocks
// pushing 8 MB of sc1 stores was ~20x slower than 16 blocks of normal
// cached in-place stores + dispatch-boundary publication. Keep the scan as
// its own dispatch.
template <typename T>
__device__ __forceinline__ void st_c(T* p, T v) {
    __hip_atomic_store(p, v, __ATOMIC_RELAXED, __HIP_MEMORY_SCOPE_AGENT);
}

// R12 sharded flat barrier (256 co-resident blocks), agent-scope ONLY:
// arrival on 32 line-padded counters (8 blocks each, parallel across LLC
// banks); group closers RMW the master; everyone polls the master.
__device__ __forceinline__ void gbar(int* ctrs, int round) {
    asm volatile("s_waitcnt vmcnt(0)" ::: "memory");
    __syncthreads();
    if (threadIdx.x == 0) {
        int g = blockIdx.x >> 3;      // 0..31, 8 blocks each
        int a = __hip_atomic_fetch_add(&ctrs[32 * (1 + g)], 1,
                                       __ATOMIC_RELAXED, __HIP_MEMORY_SCOPE_AGENT);
        if (a == 8 * round - 1)       // group closer
            __hip_atomic_fetch_add(&ctrs[0], 1, __ATOMIC_RELAXED,
                                   __HIP_MEMORY_SCOPE_AGENT);
        while (__hip_atomic_load(&ctrs[0], __ATOMIC_RELAXED,
                                 __HIP_MEMORY_SCOPE_AGENT) < 32 * round)
            __builtin_amdgcn_s_sleep(2);
    }
    __syncthreads();
}

// ---------------- kernels ---------------------------------------------------

// staging, PURE (verified R13-session body; <41 us measured via R16's split).
// Normal cached stores of Cc + part, published by the dispatch boundary.
// R18: block 0 additionally zeroes the 64 line-padded barrier counters via
// sc1 (saves the memset dispatch + its gap; correctness-validated in R17 —
// ordered before k_tail's barrier use by the two dispatch boundaries).
__global__ void __launch_bounds__(256) k_stage(const float* __restrict__ probs,
        const float* __restrict__ bbox,
        double* __restrict__ part, float* __restrict__ Cc, int* __restrict__ ctrs) {
    __shared__ int xlo_s[CROWS], xhi_s[CROWS];
    __shared__ int2 rng_s[CROWS];   // {q0, q1} col-quad range; {1,0} if unflagged
    int tid = blockIdx.x * 256 + threadIdx.x;   // NCHUNK * WW/4 threads
    int c  = tid >> 10;          // chunk (uniform per block)
    int xq = tid & 1023;         // col-quad index
    int t  = threadIdx.x;
    if (blockIdx.x == 0 && t < 64) st_c(&ctrs[t * 32], 0);   // all counter lines
    if (t < CROWS) { xlo_s[t] = WW + 1; xhi_s[t] = -1; }
    __syncthreads();
    int r0 = c * CROWS;
    for (int i = t; i < NB; i += 256) {
        float4 bb = ((const float4*)bbox)[i];
        int x1 = min(max((int)floorf(bb.x), 0), WW);
        int y1 = min(max((int)floorf(bb.y), 0), HH);
        int x2 = min(max((int)floorf(bb.z), 0), WW);
        int y2 = min(max((int)floorf(bb.w), 0), HH);
        int ra = y1 - 1 - r0, rb = y2 - 1 - r0;
        if (ra >= 0 && ra < CROWS) { atomicMin(&xlo_s[ra], x1); atomicMax(&xhi_s[ra], x2); }
        if (rb >= 0 && rb < CROWS) { atomicMin(&xlo_s[rb], x1); atomicMax(&xhi_s[rb], x2); }
    }
    __syncthreads();
    if (t < CROWS) {
        int lo = xlo_s[t], hi = xhi_s[t];
        rng_s[t] = (hi >= 0) ? make_int2(lo >> 2, (hi + 3) >> 2) : make_int2(1, 0);
    }
    __syncthreads();
    const float4* p = (const float4*)probs + (size_t)r0 * (WW / 4) + xq;
    float4* Cc4 = (float4*)Cc;
    double a0 = 0.0, a1 = 0.0, a2 = 0.0, a3 = 0.0;
    for (int r = 0; r < CROWS; r += 8) {
        float4 q[8];
        #pragma unroll
        for (int k = 0; k < 8; k++) q[k] = p[(size_t)(r + k) * (WW / 4)];
        #pragma unroll
        for (int k = 0; k < 8; k++) {
            a0 += (double)q[k].x; a1 += (double)q[k].y;
            a2 += (double)q[k].z; a3 += (double)q[k].w;
            int2 d = rng_s[r + k];
            if (xq >= d.x && xq < d.y)
                Cc4[(size_t)(r0 + r + k) * (WW / 4) + xq] =
                    make_float4((float)a0, (float)a1, (float)a2, (float)a3);
        }
    }
    double2* pp = (double2*)(part + (size_t)c * WW) + xq * 2;
    pp[0] = make_double2(a0, a1);
    pp[1] = make_double2(a2, a3);
}

// in-place exclusive scan of part along the chunk axis, per column,
// COALESCED — byte-identical to the original session's ~3 us kernel.
// 16 blocks x 256 threads, thread owns a column. Normal cached stores,
// published to k_tail by the dispatch boundary (the R17 in-kernel sc1
// version of this was ~20x slower — keep it as its own dispatch).
__global__ void k_chunkscan(double* __restrict__ part) {
    int x = blockIdx.x * blockDim.x + threadIdx.x;   // WW threads
    double carry = 0.0;
    for (int g = 0; g < NCHUNK / 16; g++) {
        double v[16];
        #pragma unroll
        for (int k = 0; k < 16; k++) v[k] = part[(size_t)(g * 16 + k) * WW + x];
        #pragma unroll
        for (int k = 0; k < 16; k++) { double tv = v[k]; v[k] = carry; carry += tv; }
        #pragma unroll
        for (int k = 0; k < 16; k++) part[(size_t)(g * 16 + k) * WW + x] = v[k];
    }
}

// fused tail (R12/R16 phases verbatim; reads in-place-scanned part): boxsum
// -> rank -> iou -> group -> final. 256 blocks x 1024 threads (16 waves/CU),
// 4 sharded barriers. P4 stages full ioub into LDS (serial greedy chain
// reads ~120cy LDS instead of ~900cy cold global).
__global__ void __launch_bounds__(1024) k_tail(const float* __restrict__ bbox,
        const float* __restrict__ obj,
        const float* __restrict__ Cc,
        const double* __restrict__ part,
        const int* __restrict__ counts,
        double* __restrict__ sc64, int* __restrict__ order,
        u64* __restrict__ ioub, double* __restrict__ recsc,
        u64* __restrict__ recsel, int* __restrict__ ctrs,
        float* __restrict__ out) {
    __shared__ double s_sc[NB];                 // 8 KB, unsorted scores
    __shared__ int    ord_s[NB];                // 4 KB, sorted->orig index
    __shared__ alignas(16) u64 big[NB * 16];    // 128 KB: sbb (P3) / iou rows (P4)
    __shared__ double red[16];                  // P1 cross-wave reduce
    __shared__ int    redi[16];                 // P2 cross-wave reduce
    float4* sbb = (float4*)big;                 // first 16 KB alias
    int b = blockIdx.x, t = threadIdx.x;

    // ---- P1: boxsum, 4 boxes/block x 256 threads each. Column value =
    // within-chunk fp32 cumsum row (Cc) + fp64 chunk prefix (part, in-place
    // scanned, 16-row chunks -> index (y-1)>>4), normal cacheable loads.
    {
        int bg = t >> 8;            // box group 0..3 (waves 4bg..4bg+3)
        int tl = t & 255;
        int i = b * 4 + bg;
        float4 bb = ((const float4*)bbox)[i];
        int x1 = min(max((int)floorf(bb.x), 0), WW);
        int y1 = min(max((int)floorf(bb.y), 0), HH);
        int x2 = min(max((int)floorf(bb.z), 0), WW);
        int y2 = min(max((int)floorf(bb.w), 0), HH);
        bool h1 = (y1 >= 1), h2 = (y2 >= 1);
        const float*  r2 = Cc   + (size_t)(h2 ? (y2 - 1) : 0) * WW;
        const double* q2 = part + (size_t)(h2 ? ((y2 - 1) >> 4) : 0) * WW;
        const float*  r1 = Cc   + (size_t)(h1 ? (y1 - 1) : 0) * WW;
        const double* q1 = part + (size_t)(h1 ? ((y1 - 1) >> 4) : 0) * WW;
        double s = 0.0;
        for (int x = x1 + tl; x < x2; x += 256) {
            double v2 = h2 ? ((double)r2[x] + q2[x]) : 0.0;
            double v1 = h1 ? ((double)r1[x] + q1[x]) : 0.0;
            s += (v2 - v1);
        }
        #pragma unroll
        for (int off = 32; off > 0; off >>= 1) s += __shfl_down(s, off);
        if ((t & 63) == 0) red[t >> 6] = s;
        __syncthreads();
        if (tl == 0) {
            double tot = red[bg * 4] + red[bg * 4 + 1] + red[bg * 4 + 2] + red[bg * 4 + 3];
            long long cnt = (long long)(y2 - y1) * (long long)(x2 - x1);
            if (cnt < 1) cnt = 1;
            st_c(&sc64[i], 0.5 * ((double)obj[i] + tot / (double)cnt));
        }
    }
    gbar(ctrs, 1);

    // ---- P2: stable descending rank, DISTRIBUTED: 4 boxes/block, 256
    // threads per box, 4 j's per thread; shuffle + LDS reduce -> sc1 order.
    s_sc[t] = sc64[t];              // normal loads (sc1-written, fresh)
    __syncthreads();
    {
        int bg = t >> 8;            // box slot 0..3
        int tl = t & 255;
        int i = b * 4 + bg;
        double si = s_sc[i];
        int p = 0;
        #pragma unroll
        for (int it = 0; it < 4; it++) {
            int j = tl * 4 + it;
            double sj = s_sc[j];
            p += (sj > si) || (sj == si && j < i);
        }
        #pragma unroll
        for (int off = 32; off > 0; off >>= 1) p += __shfl_down(p, off);
        if ((t & 63) == 0) redi[t >> 6] = p;
        __syncthreads();
        if (t < 4) {
            int r = redi[t * 4] + redi[t * 4 + 1] + redi[t * 4 + 2] + redi[t * 4 + 3];
            st_c(&order[r], b * 4 + t);
        }
    }
    gbar(ctrs, 2);

    // ---- P3: IoU(sorted_i, sorted_j) > 0.5 bit matrix; 4 rows/block.
    // Full order gathered (fresh buffer, 4 KB) + sorted bboxes into LDS.
    {
        int o = order[t];           // normal load
        ord_s[t] = o;
        sbb[t] = ((const float4*)bbox)[o];
    }
    __syncthreads();
    {
        int l = t & 63;
        for (int task = t >> 6; task < 64; task += 16) {
            int r = task >> 4, wd = task & 15;
            int i = b * 4 + r;
            float4 a = sbb[i];
            float ai = (a.z - a.x) * (a.w - a.y);
            float4 bb = sbb[(wd << 6) + l];
            float aj = (bb.z - bb.x) * (bb.w - bb.y);
            float ix1 = fmaxf(a.x, bb.x), iy1 = fmaxf(a.y, bb.y);
            float ix2 = fminf(a.z, bb.z), iy2 = fminf(a.w, bb.w);
            float iw = fmaxf(ix2 - ix1, 0.0f), ih = fmaxf(iy2 - iy1, 0.0f);
            float inter = iw * ih;
            float iou_v = inter / (ai + aj - inter);
            u64 m = __ballot(iou_v > IOU_T);
            if (l == 0) st_c(&ioub[(size_t)i * 16 + wd], m);
        }
    }
    gbar(ctrs, 3);

    // ---- P4: greedy grouping, 4 starts/block; FULL ioub staged into LDS
    // (coalesced 128 KB, LLC-amortized) so the serial greedy chain reads
    // ~120cy LDS rows instead of ~900cy cold global rows.
    #pragma unroll
    for (int k = 0; k < 16; k++) big[t + k * 1024] = ioub[t + k * 1024];
    __syncthreads();
    {
        int K = counts[0];
        if (t < 4) {
            int i = b * 4 + t;
            u64 inc[16], sel[16];
            int wi = i >> 6, bi = i & 63;
            #pragma unroll
            for (int w = 0; w < 16; w++) {
                inc[w] = big[i * 16 + w];
                sel[w] = (w == wi) ? (1ULL << bi) : 0ULL;
            }
            int size = 1;
            double score = s_sc[ord_s[i]];
            int last = i;
            #pragma unroll
            for (int w = 0; w < 16; w++) {
                if (w < wi || size >= K) continue;
                u64 avail = ~inc[w];
                if (w == wi) avail &= (bi == 63) ? 0ULL : (~0ULL << (bi + 1));
                while (avail != 0ULL && size < K) {
                    int bj = __builtin_ctzll(avail);
                    int j = (w << 6) + bj;
                    sel[w] |= 1ULL << bj;
                    size++;
                    score += s_sc[ord_s[j]];
                    last = j;
                    const u64* rj = &big[j * 16];
                    #pragma unroll
                    for (int w2 = 0; w2 < 16; w2++) inc[w2] |= rj[w2];
                    avail &= ~inc[w];          // row j's own bits clear bj et al.
                    avail &= ~(1ULL << bj);    // safety
                }
            }
            int rec = (size == K) && (last < NB - 1);
            st_c(&recsc[i], rec ? score : -1e300);
            #pragma unroll
            for (int w = 0; w < 16; w++) st_c(&recsel[(size_t)i * 16 + w], sel[w]);
        }
    }
    gbar(ctrs, 4);
    if (b != 0) return;

    // ---- P5: final last-argmax + output scatter (block 0, wave 0).
    if (t < 64) {
        double bs = -1e301; int bidx = 0;
        for (int m = 0; m < 16; m++) {
            int k = t * 16 + m;        // increasing k; >= keeps the last
            double v = recsc[k];       // normal load (fresh buffer)
            if (v >= bs) { bs = v; bidx = k; }
        }
        #pragma unroll
        for (int off = 32; off > 0; off >>= 1) {
            double ob = __shfl_down(bs, off);
            int oi = __shfl_down(bidx, off);
            if (ob > bs || (ob == bs && oi > bidx)) { bs = ob; bidx = oi; }
        }
        bs = __shfl(bs, 0);
        bidx = __shfl(bidx, 0);
        int any = bs > -1e299;
        for (int k = t; k < NB; k += 64) {
            float v = 0.0f;
            if (any && ((recsel[(size_t)bidx * 16 + (k >> 6)] >> (k & 63)) & 1ULL))
                v = (float)s_sc[ord_s[k]];
            out[k] = v;
        }
    }
}

// ---------------- host entry ------------------------------------------------

extern "C" void kernel_launch(void* const* d_in, const int* in_sizes, int n_in,
                              void* d_out, int out_size, void* d_ws, size_t ws_size,
                              hipStream_t stream) {
    const float* bbox  = (const float*)d_in[0];
    const float* obj   = (const float*)d_in[1];
    const float* probs = (const float*)d_in[2];
    const int*   counts = (const int*)d_in[3];
    float* out = (float*)d_out;

    char* w = (char*)d_ws;
    double* part    = (double*)(w + OFF_PART);
    double* sc64    = (double*)(w + OFF_SC64);
    int*    order   = (int*)(w + OFF_ORDER);
    int*    ctrs    = (int*)(w + OFF_CTR);
    u64*    ioub    = (u64*)(w + OFF_IOU);
    double* recsc   = (double*)(w + OFF_RECSC);
    u64*    recsel  = (u64*)(w + OFF_RECSEL);
    float*  Cc      = (float*)(w + OFF_CC);

    k_stage<<<NBLK_STAGE, 256, 0, stream>>>(probs, bbox, part, Cc, ctrs);
    k_chunkscan<<<WW / 256, 256, 0, stream>>>(part);
    k_tail<<<NBLK_TAIL, 1024, 0, stream>>>(bbox, obj, Cc, part, counts,
                                           sc64, order, ioub, recsc,
                                           recsel, ctrs, out);
}